// Round 5
// baseline (122.140 us; speedup 1.0000x reference)
//
#include <hip/hip_runtime.h>
#include <hip/hip_bf16.h>
#include <math.h>

#define B_ 4096
#define D_ 784
#define C_ 10
#define E_ 1024
#define K_ 8
#define KP 800      // D padded to multiple of 32 for MFMA
#define LDW 808     // LDS row stride (shorts) for W tile in expert_mfma
#define CAP 48      // candidate capacity in topk_select

typedef float f32x4 __attribute__((ext_vector_type(4)));
typedef short s16x8 __attribute__((ext_vector_type(8)));

// ---------------- fp32 -> bf16 with zero-pad to KP; also zeros count ----------------
__global__ __launch_bounds__(256) void prep_bf16(const float* __restrict__ src,
                                                 unsigned short* __restrict__ dst,
                                                 int nrows, int* __restrict__ count) {
  if (count && blockIdx.x == 0) {
    for (int i = threadIdx.x; i < E_; i += 256) count[i] = 0;
  }
  int t   = blockIdx.x * 256 + threadIdx.x;   // one thread per 8-element chunk
  int row = t / (KP / 8);
  int ch  = t % (KP / 8);                     // 0..99; 98,99 are zero-pad
  if (row >= nrows) return;
  unsigned short u[8];
  if (ch < 98) {
    const float* s = src + (size_t)row * D_ + ch * 8;
    #pragma unroll
    for (int i = 0; i < 8; ++i) {
      __hip_bfloat16 h = __float2bfloat16(s[i]);
      u[i] = *(unsigned short*)&h;
    }
  } else {
    #pragma unroll
    for (int i = 0; i < 8; ++i) u[i] = 0;
  }
  *(uint4*)(dst + (size_t)row * KP + ch * 8) = *(uint4*)u;
}

// ---- build stacked head weights [32][KP] bf16: rows 0-9 Wv, rows 16-25 Wt (rest zero) ----
__global__ __launch_bounds__(256) void prep_whead(const float* __restrict__ Wv,
                                                  const float* __restrict__ Wt,
                                                  unsigned short* __restrict__ Wh) {
  int t = blockIdx.x * 256 + threadIdx.x;     // chunk over 32*100
  if (t >= 32 * 100) return;
  int r = t / 100, kc = (t % 100) * 8;
  unsigned short u[8];
  const float* src = nullptr;
  if (r < 10) src = Wv + (size_t)r * D_ + kc;
  else if (r >= 16 && r < 26) src = Wt + (size_t)(r - 16) * D_ + kc;
  if (src && kc < 784) {
    #pragma unroll
    for (int i = 0; i < 8; ++i) {
      __hip_bfloat16 h = __float2bfloat16(src[i]);
      u[i] = *(unsigned short*)&h;
    }
  } else {
    #pragma unroll
    for (int i = 0; i < 8; ++i) u[i] = 0;
  }
  *(uint4*)(Wh + (size_t)r * KP + kc) = *(uint4*)u;
}

// ---------------- approx dot = bf16(x) @ bf16(keys)^T ----------------
__global__ __launch_bounds__(256) void gemm_bf16(const unsigned short* __restrict__ xh,
                                                 const unsigned short* __restrict__ kh,
                                                 float* __restrict__ cosb) {
  __shared__ unsigned short As[64 * 40];
  __shared__ unsigned short Bs[64 * 40];
  const int tid  = threadIdx.x;
  const int row0 = blockIdx.y * 64, col0 = blockIdx.x * 64;
  const int srow = tid >> 2, sch = tid & 3;
  const int lane = tid & 63, w = tid >> 6;
  const int wr = (w >> 1) * 32, wc = (w & 1) * 32;
  const int fr = lane & 15, fg = lane >> 4;

  const unsigned short* gx = xh + (size_t)(row0 + srow) * KP + sch * 8;
  const unsigned short* gk = kh + (size_t)(col0 + srow) * KP + sch * 8;
  unsigned short* sa = As + srow * 40 + sch * 8;
  unsigned short* sb = Bs + srow * 40 + sch * 8;
  const unsigned short* pa0 = As + (wr + fr) * 40 + fg * 8;
  const unsigned short* pb0 = Bs + (wc + fr) * 40 + fg * 8;

  f32x4 acc[2][2] = {};
  for (int k0 = 0; k0 < KP; k0 += 32) {
    uint4 va = *(const uint4*)(gx + k0);
    uint4 vb = *(const uint4*)(gk + k0);
    __syncthreads();
    *(uint4*)sa = va;
    *(uint4*)sb = vb;
    __syncthreads();
    s16x8 a0 = *(const s16x8*)(pa0);
    s16x8 a1 = *(const s16x8*)(pa0 + 16 * 40);
    s16x8 b0 = *(const s16x8*)(pb0);
    s16x8 b1 = *(const s16x8*)(pb0 + 16 * 40);
    acc[0][0] = __builtin_amdgcn_mfma_f32_16x16x32_bf16(a0, b0, acc[0][0], 0, 0, 0);
    acc[0][1] = __builtin_amdgcn_mfma_f32_16x16x32_bf16(a0, b1, acc[0][1], 0, 0, 0);
    acc[1][0] = __builtin_amdgcn_mfma_f32_16x16x32_bf16(a1, b0, acc[1][0], 0, 0, 0);
    acc[1][1] = __builtin_amdgcn_mfma_f32_16x16x32_bf16(a1, b1, acc[1][1], 0, 0, 0);
  }
  #pragma unroll
  for (int m = 0; m < 2; ++m)
    #pragma unroll
    for (int n = 0; n < 2; ++n)
      #pragma unroll
      for (int j = 0; j < 4; ++j) {
        int r = row0 + wr + m * 16 + fg * 4 + j;
        int c = col0 + wc + n * 16 + fr;
        cosb[(size_t)r * E_ + c] = acc[m][n][j];
      }
}

// ---- topk: threshold from bitonic of lane-maxima -> compact -> exact refine -> bitonic top-8 ----
__global__ __launch_bounds__(256) void topk_select(const float* __restrict__ cosb,
                                                   const float* __restrict__ x,
                                                   const float* __restrict__ keys,
                                                   float* __restrict__ sims,
                                                   int* __restrict__ gidx,
                                                   float* __restrict__ wsum,
                                                   int* __restrict__ count) {
  __shared__ int   sIdx[4][CAP];
  __shared__ float sVal[4][CAP];
  const int tid = threadIdx.x, w = tid >> 6, lane = tid & 63;
  const int row = (blockIdx.x << 2) + w;

  // load approx dots, lane-interleaved
  const float* cr = cosb + (size_t)row * E_;
  float vals[16];
  #pragma unroll
  for (int j = 0; j < 16; ++j) vals[j] = cr[j * 64 + lane];

  // per-lane max
  float lm = vals[0];
  #pragma unroll
  for (int j = 1; j < 16; ++j) lm = fmaxf(lm, vals[j]);

  // bitonic sort of 64 lane-maxima (ascending by lane)
  float v = lm;
  #pragma unroll
  for (int k = 2; k <= 64; k <<= 1) {
    #pragma unroll
    for (int j = k >> 1; j > 0; j >>= 1) {
      float o = __shfl_xor(v, j, 64);
      bool lower = (lane & j) == 0;
      bool asc = (lane & k) == 0;
      float mn = fminf(v, o), mx = fmaxf(v, o);
      v = (lower == asc) ? mn : mx;
    }
  }
  // L8 = 8th largest lane-max <= g8; margin >> bf16 dot error
  float t8 = __shfl(v, 56) - 0.06f;

  // compact candidate indices (vals >= t8) via ballot
  int cnt = 0;
  #pragma unroll
  for (int j = 0; j < 16; ++j) {
    bool p = vals[j] >= t8;
    unsigned long long mk = __ballot(p);
    if (p) {
      int pos = cnt + __popcll(mk & ((1ull << lane) - 1ull));
      if (pos < CAP) sIdx[w][pos] = j * 64 + lane;
    }
    cnt += __popcll(mk);
  }
  int m = cnt < CAP ? cnt : CAP;
  __syncthreads();

  // 1/||x|| via 4-lane strips (each group covers the full row)
  const int sl = lane & 3, g = lane >> 2;
  const float* xp = x + (size_t)row * D_ + sl * 196;
  float q = 0.f;
  for (int c = 0; c < 49; ++c) {
    float4 xv = *(const float4*)(xp + c * 4);
    q += xv.x * xv.x + xv.y * xv.y + xv.z * xv.z + xv.w * xv.w;
  }
  q += __shfl_xor(q, 1, 64);
  q += __shfl_xor(q, 2, 64);
  const float rn = 1.0f / fmaxf(sqrtf(q), 1e-12f);

  // exact fp32 dots: one candidate per 4-lane group, up to 3 passes
  #pragma unroll
  for (int p = 0; p < 3; ++p) {
    if (p * 16 < m) {                       // wave-uniform branch
      int cnum = p * 16 + g;
      bool act = cnum < m;
      int e = act ? sIdx[w][cnum] : 0;
      const float* kp = keys + (size_t)e * D_ + sl * 196;
      float s = 0.f;
      for (int c = 0; c < 49; ++c) {
        float4 kv = *(const float4*)(kp + c * 4);
        float4 xv = *(const float4*)(xp + c * 4);
        s += xv.x * kv.x + xv.y * kv.y + xv.z * kv.z + xv.w * kv.w;
      }
      s += __shfl_xor(s, 1, 64);
      s += __shfl_xor(s, 2, 64);
      if (act && sl == 0) sVal[w][cnum] = s;
    }
  }
  __syncthreads();

  // pack (exact value, ~idx) and bitonic-sort 64 keys ascending
  unsigned long long key = 0;
  if (lane < m) {
    float ev = sVal[w][lane];
    int ei = sIdx[w][lane];
    unsigned ub = __float_as_uint(ev);
    ub = (ub & 0x80000000u) ? ~ub : (ub | 0x80000000u);
    key = ((unsigned long long)ub << 32) | (unsigned)(~ei);
  }
  #pragma unroll
  for (int k = 2; k <= 64; k <<= 1) {
    #pragma unroll
    for (int j = k >> 1; j > 0; j >>= 1) {
      unsigned long long o = __shfl_xor(key, j, 64);
      bool lower = (lane & j) == 0;
      bool asc = (lane & k) == 0;
      unsigned long long mn = key < o ? key : o;
      unsigned long long mx = key < o ? o : key;
      key = (lower == asc) ? mn : mx;
    }
  }

  // lanes 56..63 hold top-8 (lane 63 best)
  if (lane >= 56) {
    unsigned ub = (unsigned)(key >> 32);
    unsigned fb = (ub & 0x80000000u) ? (ub ^ 0x80000000u) : ~ub;
    float ev = __uint_as_float(fb);
    int ei = (int)(~(unsigned)key) & (E_ - 1);
    float simv = ev * rn;
    int r = 63 - lane;                        // rank, 0 = best
    sims[row * K_ + r] = simv;
    atomicAdd(&count[ei], 1);
    float ssum = simv;
    ssum += __shfl_xor(ssum, 1, 64);
    ssum += __shfl_xor(ssum, 2, 64);
    ssum += __shfl_xor(ssum, 4, 64);
    if (lane == 56) wsum[row] = ssum;
    // ascending sort of the 8 expert ids (bitonic within lanes 56..63)
    int si = ei;
    const int l3 = lane & 7;
    #pragma unroll
    for (int k = 2; k <= 8; k <<= 1) {
      #pragma unroll
      for (int j = k >> 1; j > 0; j >>= 1) {
        int o = __shfl_xor(si, j, 64);
        bool lower = (l3 & j) == 0;
        bool asc = (l3 & k) == 0;
        int mn = si < o ? si : o;
        int mx = si < o ? o : si;
        si = (lower == asc) ? mn : mx;
      }
    }
    gidx[row * K_ + (lane - 56)] = si;
  }
}

// ---------------- exclusive scan of expert counts (single wave) ----------------
__global__ __launch_bounds__(64) void scan_wave(const int* __restrict__ count,
                                                int* __restrict__ offset,
                                                int* __restrict__ cursor) {
  int lane = threadIdx.x;
  int c[16], pre[16];
  int s = 0;
  #pragma unroll
  for (int i = 0; i < 16; ++i) {
    c[i] = count[lane * 16 + i];
    pre[i] = s;
    s += c[i];
  }
  int tot = s;
  #pragma unroll
  for (int off = 1; off < 64; off <<= 1) {
    int o = __shfl_up(tot, off, 64);
    if (lane >= off) tot += o;
  }
  int ex = tot - s;
  #pragma unroll
  for (int i = 0; i < 16; ++i) {
    offset[lane * 16 + i] = ex + pre[i];
    cursor[lane * 16 + i] = ex + pre[i];
  }
}

// ---------------- scatter (b,k) pairs into per-expert lists ----------------
__global__ __launch_bounds__(256) void fill_kernel(const int* __restrict__ gidx,
                                                   int* __restrict__ cursor,
                                                   int* __restrict__ list) {
  int t = blockIdx.x * 256 + threadIdx.x;
  if (t >= B_ * K_) return;
  int e = gidx[t];
  int p = atomicAdd(&cursor[e], 1);
  list[p] = t;                               // order irrelevant: output slot is t
}

// ---------------- per-expert bf16 MFMA: X_e[n,784] @ W_e^T -> tanh -> slot ----------------
__global__ __launch_bounds__(256) void expert_mfma(const float* __restrict__ Wm,
                                                   const float* __restrict__ bm,
                                                   const unsigned short* __restrict__ xh,
                                                   const int* __restrict__ list,
                                                   const int* __restrict__ offset,
                                                   const int* __restrict__ count,
                                                   float* __restrict__ slot) {
  __shared__ unsigned short Wl[16 * LDW];
  const int e   = blockIdx.x;
  const int tid = threadIdx.x;
  const int n = count[e], base = offset[e];

  for (int ch = tid; ch < 1600; ch += 256) {
    int r  = ch / 100;
    int kc = (ch % 100) * 8;
    unsigned short u[8];
    if (r < 10 && kc < 784) {
      const float* src = Wm + (size_t)e * (C_ * D_) + r * D_ + kc;
      #pragma unroll
      for (int i = 0; i < 8; ++i) {
        __hip_bfloat16 h = __float2bfloat16(src[i]);
        u[i] = *(unsigned short*)&h;
      }
    } else {
      #pragma unroll
      for (int i = 0; i < 8; ++i) u[i] = 0;
    }
    *(uint4*)(Wl + r * LDW + kc) = *(uint4*)u;
  }
  __syncthreads();
  if (n == 0) return;

  const int lane = tid & 63, w = tid >> 6;
  const int fr = lane & 15, fg = lane >> 4;
  const float bias = (fr < C_) ? bm[e * C_ + fr] : 0.f;
  const unsigned short* bp = Wl + fr * LDW + fg * 8;

  for (int c0 = w * 16; c0 < n; c0 += 64) {
    int sidx = c0 + fr;
    int item = (sidx < n) ? list[base + sidx] : list[base];
    const unsigned short* xrow = xh + (size_t)(item >> 3) * KP + fg * 8;
    f32x4 acc = {};
    #pragma unroll
    for (int k0 = 0; k0 < KP; k0 += 32) {
      s16x8 a = *(const s16x8*)(xrow + k0);
      s16x8 b = *(const s16x8*)(bp + k0);
      acc = __builtin_amdgcn_mfma_f32_16x16x32_bf16(a, b, acc, 0, 0, 0);
    }
    if (fr < C_) {
      #pragma unroll
      for (int j = 0; j < 4; ++j) {
        int s2 = c0 + fg * 4 + j;
        if (s2 < n) {
          int it2 = list[base + s2];
          slot[(size_t)it2 * C_ + fr] = tanhf((acc[j] + bias) * 0.1f) * 10.0f;
        }
      }
    }
  }
}

// ---------------- weighted reduce of expert outputs ----------------
__global__ __launch_bounds__(256) void reduce_kernel(const float* __restrict__ slot,
                                                     const float* __restrict__ sims,
                                                     const float* __restrict__ wsum,
                                                     float* __restrict__ out) {
  int b = blockIdx.x * 256 + threadIdx.x;
  if (b >= B_) return;
  float ens[C_];
  #pragma unroll
  for (int c = 0; c < C_; ++c) ens[c] = 0.f;
  #pragma unroll
  for (int k = 0; k < K_; ++k) {
    float wv = sims[b * K_ + k];
    const float* sl = slot + (size_t)(b * K_ + k) * C_;
    #pragma unroll
    for (int c = 0; c < C_; ++c) ens[c] += sl[c] * wv;
  }
  float ws = wsum[b];
  #pragma unroll
  for (int c = 0; c < C_; ++c) out[(size_t)b * C_ + c] = ens[c] / ws;
}

// ---------------- heads via MFMA: logits = xh @ Wh^T; softmax across 16-lane group ----
__global__ __launch_bounds__(256) void heads_mfma(const unsigned short* __restrict__ xh,
                                                  const unsigned short* __restrict__ Wh,
                                                  const float* __restrict__ bv,
                                                  const float* __restrict__ bt,
                                                  float* __restrict__ out_tanh,
                                                  float* __restrict__ out_van) {
  const int tid = threadIdx.x, w = tid >> 6, lane = tid & 63;
  const int fr = lane & 15, fg = lane >> 4;
  const int rbase = blockIdx.x * 64 + w * 16;
  const unsigned short* ar  = xh + (size_t)(rbase + fr) * KP + fg * 8;
  const unsigned short* b0p = Wh + (size_t)fr * KP + fg * 8;
  const unsigned short* b1p = Wh + (size_t)(fr + 16) * KP + fg * 8;
  f32x4 acc0 = {}, acc1 = {};
  #pragma unroll 5
  for (int k0 = 0; k0 < KP; k0 += 32) {
    s16x8 a  = *(const s16x8*)(ar + k0);
    s16x8 b0 = *(const s16x8*)(b0p + k0);
    s16x8 b1 = *(const s16x8*)(b1p + k0);
    acc0 = __builtin_amdgcn_mfma_f32_16x16x32_bf16(a, b0, acc0, 0, 0, 0);
    acc1 = __builtin_amdgcn_mfma_f32_16x16x32_bf16(a, b1, acc1, 0, 0, 0);
  }
  const float bvv = (fr < C_) ? bv[fr] : 0.f;
  const float btv = (fr < C_) ? bt[fr] : 0.f;
  #pragma unroll
  for (int j = 0; j < 4; ++j) {
    int r = rbase + fg * 4 + j;
    float vv = acc0[j] + bvv;
    float tv = acc1[j] + btv;
    float mv = (fr < C_) ? vv : -__builtin_inff();
    #pragma unroll
    for (int off = 1; off < 16; off <<= 1) mv = fmaxf(mv, __shfl_xor(mv, off, 64));
    float ev = (fr < C_) ? expf(vv - mv) : 0.f;
    float se = ev;
    #pragma unroll
    for (int off = 1; off < 16; off <<= 1) se += __shfl_xor(se, off, 64);
    float lse = mv + logf(se);
    if (fr < C_) {
      out_van[(size_t)r * C_ + fr]  = vv - lse;
      out_tanh[(size_t)r * C_ + fr] = tanhf(tv * 0.1f) * 10.0f;
    }
  }
}

extern "C" void kernel_launch(void* const* d_in, const int* in_sizes, int n_in,
                              void* d_out, int out_size, void* d_ws, size_t ws_size,
                              hipStream_t stream) {
  const float* x    = (const float*)d_in[0];
  const float* keys = (const float*)d_in[1];
  const float* Wm   = (const float*)d_in[2];
  const float* bm   = (const float*)d_in[3];
  const float* Wv   = (const float*)d_in[4];
  const float* bv   = (const float*)d_in[5];
  const float* Wt   = (const float*)d_in[6];
  const float* bt   = (const float*)d_in[7];
  float* out = (float*)d_out;

  char* p = (char*)d_ws;
  auto carve = [&](size_t bytes) { char* q = p; p += (bytes + 255) & ~(size_t)255; return q; };
  float* cosb  = (float*)carve((size_t)B_ * E_ * 4);
  float* sims  = (float*)carve(B_ * K_ * 4);
  float* wsumb = (float*)carve(B_ * 4);
  int*   gidx  = (int*)carve(B_ * K_ * 4);
  unsigned short* xh = (unsigned short*)carve((size_t)B_ * KP * 2);
  unsigned short* kh = (unsigned short*)carve((size_t)E_ * KP * 2);
  unsigned short* Wh = (unsigned short*)carve((size_t)32 * KP * 2);
  int*   count  = (int*)carve(E_ * 4);
  int*   offset = (int*)carve(E_ * 4);
  int*   cursor = (int*)carve(E_ * 4);
  int*   list   = (int*)carve(B_ * K_ * 4);
  float* slot   = (float*)carve((size_t)B_ * K_ * C_ * 4);

  prep_bf16<<<(B_ * (KP / 8) + 255) / 256, 256, 0, stream>>>(x, xh, B_, count);
  prep_bf16<<<(E_ * (KP / 8) + 255) / 256, 256, 0, stream>>>(keys, kh, E_, nullptr);
  prep_whead<<<(32 * 100 + 255) / 256, 256, 0, stream>>>(Wv, Wt, Wh);
  dim3 g(E_ / 64, B_ / 64);
  gemm_bf16<<<g, 256, 0, stream>>>(xh, kh, cosb);
  topk_select<<<B_ / 4, 256, 0, stream>>>(cosb, x, keys, sims, gidx, wsumb, count);
  scan_wave<<<1, 64, 0, stream>>>(count, offset, cursor);
  fill_kernel<<<(B_ * K_ + 255) / 256, 256, 0, stream>>>(gidx, cursor, list);
  expert_mfma<<<E_, 256, 0, stream>>>(Wm, bm, xh, list, offset, count, slot);
  reduce_kernel<<<(B_ + 255) / 256, 256, 0, stream>>>(slot, sims, wsumb, out);
  heads_mfma<<<B_ / 64, 256, 0, stream>>>(xh, Wh, bv, bt,
                                          out + (size_t)B_ * C_,
                                          out + 2 * (size_t)B_ * C_);
}

// Round 6
// 102.583 us; speedup vs baseline: 1.1906x; 1.1906x over previous
//
#include <hip/hip_runtime.h>
#include <hip/hip_bf16.h>
#include <math.h>

#define B_ 4096
#define D_ 784
#define C_ 10
#define E_ 1024
#define K_ 8
#define KP 800      // D padded to multiple of 32 for MFMA
#define LDW 808     // LDS row stride (shorts) for W tile in expert_mfma
#define CAP 48      // candidate capacity in topk_select

typedef float f32x4 __attribute__((ext_vector_type(4)));
typedef short s16x8 __attribute__((ext_vector_type(8)));

__device__ __forceinline__ float wave_reduce_sum(float v) {
  #pragma unroll
  for (int off = 32; off > 0; off >>= 1) v += __shfl_xor(v, off, 64);
  return v;
}

// ---------------- fp32 -> bf16 with zero-pad to KP; also zeros count ----------------
__global__ __launch_bounds__(256) void prep_bf16(const float* __restrict__ src,
                                                 unsigned short* __restrict__ dst,
                                                 int nrows, int* __restrict__ count) {
  if (count && blockIdx.x == 0) {
    for (int i = threadIdx.x; i < E_; i += 256) count[i] = 0;
  }
  int t   = blockIdx.x * 256 + threadIdx.x;   // one thread per 8-element chunk
  int row = t / (KP / 8);
  int ch  = t % (KP / 8);                     // 0..99; 98,99 are zero-pad
  if (row >= nrows) return;
  unsigned short u[8];
  if (ch < 98) {
    const float* s = src + (size_t)row * D_ + ch * 8;
    #pragma unroll
    for (int i = 0; i < 8; ++i) {
      __hip_bfloat16 h = __float2bfloat16(s[i]);
      u[i] = *(unsigned short*)&h;
    }
  } else {
    #pragma unroll
    for (int i = 0; i < 8; ++i) u[i] = 0;
  }
  *(uint4*)(dst + (size_t)row * KP + ch * 8) = *(uint4*)u;
}

// ---- build stacked head weights [32][KP] bf16: rows 0-9 Wv, rows 16-25 Wt (rest zero) ----
__global__ __launch_bounds__(256) void prep_whead(const float* __restrict__ Wv,
                                                  const float* __restrict__ Wt,
                                                  unsigned short* __restrict__ Wh) {
  int t = blockIdx.x * 256 + threadIdx.x;     // chunk over 32*100
  if (t >= 32 * 100) return;
  int r = t / 100, kc = (t % 100) * 8;
  unsigned short u[8];
  const float* src = nullptr;
  if (r < 10) src = Wv + (size_t)r * D_ + kc;
  else if (r >= 16 && r < 26) src = Wt + (size_t)(r - 16) * D_ + kc;
  if (src && kc < 784) {
    #pragma unroll
    for (int i = 0; i < 8; ++i) {
      __hip_bfloat16 h = __float2bfloat16(src[i]);
      u[i] = *(unsigned short*)&h;
    }
  } else {
    #pragma unroll
    for (int i = 0; i < 8; ++i) u[i] = 0;
  }
  *(uint4*)(Wh + (size_t)r * KP + kc) = *(uint4*)u;
}

// ---------------- approx dot = bf16(x) @ bf16(keys)^T ----------------
__global__ __launch_bounds__(256) void gemm_bf16(const unsigned short* __restrict__ xh,
                                                 const unsigned short* __restrict__ kh,
                                                 float* __restrict__ cosb) {
  __shared__ unsigned short As[64 * 40];
  __shared__ unsigned short Bs[64 * 40];
  const int tid  = threadIdx.x;
  const int row0 = blockIdx.y * 64, col0 = blockIdx.x * 64;
  const int srow = tid >> 2, sch = tid & 3;
  const int lane = tid & 63, w = tid >> 6;
  const int wr = (w >> 1) * 32, wc = (w & 1) * 32;
  const int fr = lane & 15, fg = lane >> 4;

  const unsigned short* gx = xh + (size_t)(row0 + srow) * KP + sch * 8;
  const unsigned short* gk = kh + (size_t)(col0 + srow) * KP + sch * 8;
  unsigned short* sa = As + srow * 40 + sch * 8;
  unsigned short* sb = Bs + srow * 40 + sch * 8;
  const unsigned short* pa0 = As + (wr + fr) * 40 + fg * 8;
  const unsigned short* pb0 = Bs + (wc + fr) * 40 + fg * 8;

  f32x4 acc[2][2] = {};
  for (int k0 = 0; k0 < KP; k0 += 32) {
    uint4 va = *(const uint4*)(gx + k0);
    uint4 vb = *(const uint4*)(gk + k0);
    __syncthreads();
    *(uint4*)sa = va;
    *(uint4*)sb = vb;
    __syncthreads();
    s16x8 a0 = *(const s16x8*)(pa0);
    s16x8 a1 = *(const s16x8*)(pa0 + 16 * 40);
    s16x8 b0 = *(const s16x8*)(pb0);
    s16x8 b1 = *(const s16x8*)(pb0 + 16 * 40);
    acc[0][0] = __builtin_amdgcn_mfma_f32_16x16x32_bf16(a0, b0, acc[0][0], 0, 0, 0);
    acc[0][1] = __builtin_amdgcn_mfma_f32_16x16x32_bf16(a0, b1, acc[0][1], 0, 0, 0);
    acc[1][0] = __builtin_amdgcn_mfma_f32_16x16x32_bf16(a1, b0, acc[1][0], 0, 0, 0);
    acc[1][1] = __builtin_amdgcn_mfma_f32_16x16x32_bf16(a1, b1, acc[1][1], 0, 0, 0);
  }
  #pragma unroll
  for (int m = 0; m < 2; ++m)
    #pragma unroll
    for (int n = 0; n < 2; ++n)
      #pragma unroll
      for (int j = 0; j < 4; ++j) {
        int r = row0 + wr + m * 16 + fg * 4 + j;
        int c = col0 + wc + n * 16 + fr;
        cosb[(size_t)r * E_ + c] = acc[m][n][j];
      }
}

// ---- topk: one row per block; bitonic threshold -> LDS compact -> wave-per-candidate
//      coalesced fp32 refine -> bitonic top-8 ----
__global__ __launch_bounds__(256) void topk_select(const float* __restrict__ cosb,
                                                   const float* __restrict__ x,
                                                   const float* __restrict__ keys,
                                                   float* __restrict__ sims,
                                                   int* __restrict__ gidx,
                                                   float* __restrict__ wsum,
                                                   int* __restrict__ count) {
  __shared__ float sTop[32];
  __shared__ int   sIdx[CAP];
  __shared__ float sVal[CAP];
  __shared__ int   sCnt;
  __shared__ float sT8;
  const int tid = threadIdx.x, w = tid >> 6, lane = tid & 63;
  const int row = blockIdx.x;
  if (tid == 0) sCnt = 0;

  // load 4 cos values per thread, coalesced
  const float* cr = cosb + (size_t)row * E_;
  float vals[4];
  #pragma unroll
  for (int j = 0; j < 4; ++j) vals[j] = cr[j * 256 + tid];
  float lm = fmaxf(fmaxf(vals[0], vals[1]), fmaxf(vals[2], vals[3]));

  // per-wave bitonic sort of thread-maxima (ascending by lane)
  float v = lm;
  #pragma unroll
  for (int k = 2; k <= 64; k <<= 1) {
    #pragma unroll
    for (int j = k >> 1; j > 0; j >>= 1) {
      float o = __shfl_xor(v, j, 64);
      bool lower = (lane & j) == 0;
      bool asc = (lane & k) == 0;
      float mn = fminf(v, o), mx = fmaxf(v, o);
      v = (lower == asc) ? mn : mx;
    }
  }
  if (lane >= 56) sTop[w * 8 + (lane - 56)] = v;    // each wave's top-8
  __syncthreads();

  // wave 0: 8th largest of the 32 wave-top values -> threshold
  if (w == 0) {
    float u = (lane < 32) ? sTop[lane] : -__builtin_inff();
    #pragma unroll
    for (int k = 2; k <= 64; k <<= 1) {
      #pragma unroll
      for (int j = k >> 1; j > 0; j >>= 1) {
        float o = __shfl_xor(u, j, 64);
        bool lower = (lane & j) == 0;
        bool asc = (lane & k) == 0;
        float mn = fminf(u, o), mx = fmaxf(u, o);
        u = (lower == asc) ? mn : mx;
      }
    }
    if (lane == 56) sT8 = u - 0.06f;   // margin >> bf16 dot error
  }
  __syncthreads();
  const float t8 = sT8;

  // compact candidates >= t8 (order irrelevant; value-sort later)
  #pragma unroll
  for (int j = 0; j < 4; ++j) {
    if (vals[j] >= t8) {
      int pos = atomicAdd(&sCnt, 1);
      if (pos < CAP) sIdx[pos] = j * 256 + tid;
    }
  }
  __syncthreads();
  const int m = sCnt < CAP ? sCnt : CAP;

  // x row in registers (per wave) + rnorm
  const float4* xp4 = (const float4*)(x + (size_t)row * D_);
  float4 xr[4];
  #pragma unroll
  for (int i = 0; i < 3; ++i) xr[i] = xp4[i * 64 + lane];
  xr[3] = make_float4(0.f, 0.f, 0.f, 0.f);
  if (lane < 4) xr[3] = xp4[192 + lane];
  float q = 0.f;
  #pragma unroll
  for (int i = 0; i < 4; ++i)
    q += xr[i].x * xr[i].x + xr[i].y * xr[i].y + xr[i].z * xr[i].z + xr[i].w * xr[i].w;
  q = wave_reduce_sum(q);
  const float rn = 1.0f / fmaxf(sqrtf(q), 1e-12f);

  // exact fp32 dots: one candidate per wave, coalesced key-row reads
  for (int c = w; c < m; c += 4) {
    const float4* kp4 = (const float4*)(keys + (size_t)sIdx[c] * D_);
    float s = 0.f;
    #pragma unroll
    for (int i = 0; i < 3; ++i) {
      float4 kv = kp4[i * 64 + lane];
      s += xr[i].x * kv.x + xr[i].y * kv.y + xr[i].z * kv.z + xr[i].w * kv.w;
    }
    if (lane < 4) {
      float4 kv = kp4[192 + lane];
      s += xr[3].x * kv.x + xr[3].y * kv.y + xr[3].z * kv.z + xr[3].w * kv.w;
    }
    s = wave_reduce_sum(s);
    if (lane == 0) sVal[c] = s;
  }
  __syncthreads();

  // wave 0: pack (exact value, ~idx), bitonic-sort 64 keys, emit top-8
  if (w == 0) {
    unsigned long long key = 0;
    if (lane < m) {
      float ev = sVal[lane];
      int ei = sIdx[lane];
      unsigned ub = __float_as_uint(ev);
      ub = (ub & 0x80000000u) ? ~ub : (ub | 0x80000000u);
      key = ((unsigned long long)ub << 32) | (unsigned)(~ei);
    }
    #pragma unroll
    for (int k = 2; k <= 64; k <<= 1) {
      #pragma unroll
      for (int j = k >> 1; j > 0; j >>= 1) {
        unsigned long long o = __shfl_xor(key, j, 64);
        bool lower = (lane & j) == 0;
        bool asc = (lane & k) == 0;
        unsigned long long mn = key < o ? key : o;
        unsigned long long mx = key < o ? o : key;
        key = (lower == asc) ? mn : mx;
      }
    }
    if (lane >= 56) {
      unsigned ub = (unsigned)(key >> 32);
      unsigned fb = (ub & 0x80000000u) ? (ub ^ 0x80000000u) : ~ub;
      float ev = __uint_as_float(fb);
      int ei = (int)(~(unsigned)key) & (E_ - 1);
      float simv = ev * rn;
      int r = 63 - lane;                      // rank, 0 = best
      sims[row * K_ + r] = simv;
      atomicAdd(&count[ei], 1);
      float ssum = simv;
      ssum += __shfl_xor(ssum, 1, 64);
      ssum += __shfl_xor(ssum, 2, 64);
      ssum += __shfl_xor(ssum, 4, 64);
      if (lane == 56) wsum[row] = ssum;
      // ascending sort of the 8 expert ids (bitonic within lanes 56..63)
      int si = ei;
      const int l3 = lane & 7;
      #pragma unroll
      for (int k = 2; k <= 8; k <<= 1) {
        #pragma unroll
        for (int j = k >> 1; j > 0; j >>= 1) {
          int o = __shfl_xor(si, j, 64);
          bool lower = (l3 & j) == 0;
          bool asc = (l3 & k) == 0;
          int mn = si < o ? si : o;
          int mx = si < o ? o : si;
          si = (lower == asc) ? mn : mx;
        }
      }
      gidx[row * K_ + (lane - 56)] = si;
    }
  }
}

// ---------------- exclusive scan of expert counts (single wave) ----------------
__global__ __launch_bounds__(64) void scan_wave(const int* __restrict__ count,
                                                int* __restrict__ offset,
                                                int* __restrict__ cursor) {
  int lane = threadIdx.x;
  int c[16], pre[16];
  int s = 0;
  #pragma unroll
  for (int i = 0; i < 16; ++i) {
    c[i] = count[lane * 16 + i];
    pre[i] = s;
    s += c[i];
  }
  int tot = s;
  #pragma unroll
  for (int off = 1; off < 64; off <<= 1) {
    int o = __shfl_up(tot, off, 64);
    if (lane >= off) tot += o;
  }
  int ex = tot - s;
  #pragma unroll
  for (int i = 0; i < 16; ++i) {
    offset[lane * 16 + i] = ex + pre[i];
    cursor[lane * 16 + i] = ex + pre[i];
  }
}

// ---------------- scatter (b,k) pairs into per-expert lists ----------------
__global__ __launch_bounds__(256) void fill_kernel(const int* __restrict__ gidx,
                                                   int* __restrict__ cursor,
                                                   int* __restrict__ list) {
  int t = blockIdx.x * 256 + threadIdx.x;
  if (t >= B_ * K_) return;
  int e = gidx[t];
  int p = atomicAdd(&cursor[e], 1);
  list[p] = t;                               // order irrelevant: output slot is t
}

// ---------------- per-expert bf16 MFMA: X_e[n,784] @ W_e^T -> tanh -> slot ----------------
__global__ __launch_bounds__(256) void expert_mfma(const float* __restrict__ Wm,
                                                   const float* __restrict__ bm,
                                                   const unsigned short* __restrict__ xh,
                                                   const int* __restrict__ list,
                                                   const int* __restrict__ offset,
                                                   const int* __restrict__ count,
                                                   float* __restrict__ slot) {
  __shared__ unsigned short Wl[16 * LDW];
  const int e   = blockIdx.x;
  const int tid = threadIdx.x;
  const int n = count[e], base = offset[e];

  for (int ch = tid; ch < 1600; ch += 256) {
    int r  = ch / 100;
    int kc = (ch % 100) * 8;
    unsigned short u[8];
    if (r < 10 && kc < 784) {
      const float* src = Wm + (size_t)e * (C_ * D_) + r * D_ + kc;
      #pragma unroll
      for (int i = 0; i < 8; ++i) {
        __hip_bfloat16 h = __float2bfloat16(src[i]);
        u[i] = *(unsigned short*)&h;
      }
    } else {
      #pragma unroll
      for (int i = 0; i < 8; ++i) u[i] = 0;
    }
    *(uint4*)(Wl + r * LDW + kc) = *(uint4*)u;
  }
  __syncthreads();
  if (n == 0) return;

  const int lane = tid & 63, w = tid >> 6;
  const int fr = lane & 15, fg = lane >> 4;
  const float bias = (fr < C_) ? bm[e * C_ + fr] : 0.f;
  const unsigned short* bp = Wl + fr * LDW + fg * 8;

  for (int c0 = w * 16; c0 < n; c0 += 64) {
    int sidx = c0 + fr;
    int item = (sidx < n) ? list[base + sidx] : list[base];
    const unsigned short* xrow = xh + (size_t)(item >> 3) * KP + fg * 8;
    f32x4 acc = {};
    #pragma unroll
    for (int k0 = 0; k0 < KP; k0 += 32) {
      s16x8 a = *(const s16x8*)(xrow + k0);
      s16x8 b = *(const s16x8*)(bp + k0);
      acc = __builtin_amdgcn_mfma_f32_16x16x32_bf16(a, b, acc, 0, 0, 0);
    }
    if (fr < C_) {
      #pragma unroll
      for (int j = 0; j < 4; ++j) {
        int s2 = c0 + fg * 4 + j;
        if (s2 < n) {
          int it2 = list[base + s2];
          slot[(size_t)it2 * C_ + fr] = tanhf((acc[j] + bias) * 0.1f) * 10.0f;
        }
      }
    }
  }
}

// ---------------- weighted reduce of expert outputs ----------------
__global__ __launch_bounds__(256) void reduce_kernel(const float* __restrict__ slot,
                                                     const float* __restrict__ sims,
                                                     const float* __restrict__ wsum,
                                                     float* __restrict__ out) {
  int b = blockIdx.x * 256 + threadIdx.x;
  if (b >= B_) return;
  float ens[C_];
  #pragma unroll
  for (int c = 0; c < C_; ++c) ens[c] = 0.f;
  #pragma unroll
  for (int k = 0; k < K_; ++k) {
    float wv = sims[b * K_ + k];
    const float* sl = slot + (size_t)(b * K_ + k) * C_;
    #pragma unroll
    for (int c = 0; c < C_; ++c) ens[c] += sl[c] * wv;
  }
  float ws = wsum[b];
  #pragma unroll
  for (int c = 0; c < C_; ++c) out[(size_t)b * C_ + c] = ens[c] / ws;
}

// ---------------- heads via MFMA: logits = xh @ Wh^T; softmax across 16-lane group ----
__global__ __launch_bounds__(256) void heads_mfma(const unsigned short* __restrict__ xh,
                                                  const unsigned short* __restrict__ Wh,
                                                  const float* __restrict__ bv,
                                                  const float* __restrict__ bt,
                                                  float* __restrict__ out_tanh,
                                                  float* __restrict__ out_van) {
  const int tid = threadIdx.x, w = tid >> 6, lane = tid & 63;
  const int fr = lane & 15, fg = lane >> 4;
  const int rbase = blockIdx.x * 64 + w * 16;
  const unsigned short* ar  = xh + (size_t)(rbase + fr) * KP + fg * 8;
  const unsigned short* b0p = Wh + (size_t)fr * KP + fg * 8;
  const unsigned short* b1p = Wh + (size_t)(fr + 16) * KP + fg * 8;
  f32x4 acc0 = {}, acc1 = {};
  #pragma unroll 5
  for (int k0 = 0; k0 < KP; k0 += 32) {
    s16x8 a  = *(const s16x8*)(ar + k0);
    s16x8 b0 = *(const s16x8*)(b0p + k0);
    s16x8 b1 = *(const s16x8*)(b1p + k0);
    acc0 = __builtin_amdgcn_mfma_f32_16x16x32_bf16(a, b0, acc0, 0, 0, 0);
    acc1 = __builtin_amdgcn_mfma_f32_16x16x32_bf16(a, b1, acc1, 0, 0, 0);
  }
  const float bvv = (fr < C_) ? bv[fr] : 0.f;
  const float btv = (fr < C_) ? bt[fr] : 0.f;
  #pragma unroll
  for (int j = 0; j < 4; ++j) {
    int r = rbase + fg * 4 + j;
    float vv = acc0[j] + bvv;
    float tv = acc1[j] + btv;
    float mv = (fr < C_) ? vv : -__builtin_inff();
    #pragma unroll
    for (int off = 1; off < 16; off <<= 1) mv = fmaxf(mv, __shfl_xor(mv, off, 64));
    float ev = (fr < C_) ? expf(vv - mv) : 0.f;
    float se = ev;
    #pragma unroll
    for (int off = 1; off < 16; off <<= 1) se += __shfl_xor(se, off, 64);
    float lse = mv + logf(se);
    if (fr < C_) {
      out_van[(size_t)r * C_ + fr]  = vv - lse;
      out_tanh[(size_t)r * C_ + fr] = tanhf(tv * 0.1f) * 10.0f;
    }
  }
}

extern "C" void kernel_launch(void* const* d_in, const int* in_sizes, int n_in,
                              void* d_out, int out_size, void* d_ws, size_t ws_size,
                              hipStream_t stream) {
  const float* x    = (const float*)d_in[0];
  const float* keys = (const float*)d_in[1];
  const float* Wm   = (const float*)d_in[2];
  const float* bm   = (const float*)d_in[3];
  const float* Wv   = (const float*)d_in[4];
  const float* bv   = (const float*)d_in[5];
  const float* Wt   = (const float*)d_in[6];
  const float* bt   = (const float*)d_in[7];
  float* out = (float*)d_out;

  char* p = (char*)d_ws;
  auto carve = [&](size_t bytes) { char* q = p; p += (bytes + 255) & ~(size_t)255; return q; };
  float* cosb  = (float*)carve((size_t)B_ * E_ * 4);
  float* sims  = (float*)carve(B_ * K_ * 4);
  float* wsumb = (float*)carve(B_ * 4);
  int*   gidx  = (int*)carve(B_ * K_ * 4);
  unsigned short* xh = (unsigned short*)carve((size_t)B_ * KP * 2);
  unsigned short* kh = (unsigned short*)carve((size_t)E_ * KP * 2);
  unsigned short* Wh = (unsigned short*)carve((size_t)32 * KP * 2);
  int*   count  = (int*)carve(E_ * 4);
  int*   offset = (int*)carve(E_ * 4);
  int*   cursor = (int*)carve(E_ * 4);
  int*   list   = (int*)carve(B_ * K_ * 4);
  float* slot   = (float*)carve((size_t)B_ * K_ * C_ * 4);

  prep_bf16<<<(B_ * (KP / 8) + 255) / 256, 256, 0, stream>>>(x, xh, B_, count);
  prep_bf16<<<(E_ * (KP / 8) + 255) / 256, 256, 0, stream>>>(keys, kh, E_, nullptr);
  prep_whead<<<(32 * 100 + 255) / 256, 256, 0, stream>>>(Wv, Wt, Wh);
  dim3 g(E_ / 64, B_ / 64);
  gemm_bf16<<<g, 256, 0, stream>>>(xh, kh, cosb);
  topk_select<<<B_, 256, 0, stream>>>(cosb, x, keys, sims, gidx, wsumb, count);
  scan_wave<<<1, 64, 0, stream>>>(count, offset, cursor);
  fill_kernel<<<(B_ * K_ + 255) / 256, 256, 0, stream>>>(gidx, cursor, list);
  expert_mfma<<<E_, 256, 0, stream>>>(Wm, bm, xh, list, offset, count, slot);
  reduce_kernel<<<(B_ + 255) / 256, 256, 0, stream>>>(slot, sims, wsumb, out);
  heads_mfma<<<B_ / 64, 256, 0, stream>>>(xh, Wh, bv, bt,
                                          out + (size_t)B_ * C_,
                                          out + 2 * (size_t)B_ * C_);
}

// Round 7
// 94.815 us; speedup vs baseline: 1.2882x; 1.0819x over previous
//
#include <hip/hip_runtime.h>
#include <hip/hip_bf16.h>
#include <math.h>

#define B_ 4096
#define D_ 784
#define C_ 10
#define E_ 1024
#define K_ 8
#define KP 832      // D padded to 13*64 for MFMA/BK=64
#define CHR 104     // 8-short chunks per padded row (KP/8); 98 hold data
#define LDR 72      // gemm LDS row stride (shorts): 36 dwords -> 2-way banks (free)
#define LDW 840     // expert LDS row stride (shorts): 420 dwords -> 2-way banks
#define CAP 48      // candidate capacity in topk_select
#define ECAP 128    // per-expert bucket capacity

typedef float f32x4 __attribute__((ext_vector_type(4)));
typedef short s16x8 __attribute__((ext_vector_type(8)));

__device__ __forceinline__ float wave_reduce_sum(float v) {
  #pragma unroll
  for (int off = 32; off > 0; off >>= 1) v += __shfl_xor(v, off, 64);
  return v;
}

// ---- fused prep: fp32->bf16 pad-convert x, keys, stacked head weights; zero count ----
__global__ __launch_bounds__(256) void prep_all(const float* __restrict__ x,
                                                const float* __restrict__ keys,
                                                const float* __restrict__ Wv,
                                                const float* __restrict__ Wt,
                                                unsigned short* __restrict__ xh,
                                                unsigned short* __restrict__ kh,
                                                unsigned short* __restrict__ Wh,
                                                int* __restrict__ count) {
  int gt = blockIdx.x * 256 + threadIdx.x;
  if (gt < E_) count[gt] = 0;
  int t = gt;
  const float* src = nullptr;
  unsigned short* dst;
  if (t < B_ * CHR) {
    int row = t / CHR, ch = t % CHR;
    dst = xh + (size_t)row * KP + ch * 8;
    src = (ch < 98) ? x + (size_t)row * D_ + ch * 8 : nullptr;
  } else {
    t -= B_ * CHR;
    if (t < E_ * CHR) {
      int row = t / CHR, ch = t % CHR;
      dst = kh + (size_t)row * KP + ch * 8;
      src = (ch < 98) ? keys + (size_t)row * D_ + ch * 8 : nullptr;
    } else {
      t -= E_ * CHR;
      if (t < 32 * CHR) {
        int r = t / CHR, ch = t % CHR;
        dst = Wh + (size_t)r * KP + ch * 8;
        if (ch < 98) {
          if (r < 10) src = Wv + (size_t)r * D_ + ch * 8;
          else if (r >= 16 && r < 26) src = Wt + (size_t)(r - 16) * D_ + ch * 8;
        }
      } else return;
    }
  }
  unsigned short u[8];
  if (src) {
    #pragma unroll
    for (int i = 0; i < 8; ++i) {
      __hip_bfloat16 h = __float2bfloat16(src[i]);
      u[i] = *(unsigned short*)&h;
    }
  } else {
    #pragma unroll
    for (int i = 0; i < 8; ++i) u[i] = 0;
  }
  *(uint4*)dst = *(uint4*)u;
}

// ---------------- approx dot = bf16(x) @ bf16(keys)^T, BK=64, reg prefetch ----------------
__global__ __launch_bounds__(256) void gemm_bf16(const unsigned short* __restrict__ xh,
                                                 const unsigned short* __restrict__ kh,
                                                 float* __restrict__ cosb) {
  __shared__ unsigned short As[64 * LDR];
  __shared__ unsigned short Bs[64 * LDR];
  const int tid  = threadIdx.x;
  const int row0 = blockIdx.y * 64, col0 = blockIdx.x * 64;
  const int srow = tid >> 2, sq = tid & 3;            // staging: row, quarter
  const int lane = tid & 63, w = tid >> 6;
  const int wr = (w >> 1) * 32, wc = (w & 1) * 32;
  const int fr = lane & 15, fg = lane >> 4;

  const unsigned short* gx = xh + (size_t)(row0 + srow) * KP;
  const unsigned short* gk = kh + (size_t)(col0 + srow) * KP;
  unsigned short* sa = As + srow * LDR + sq * 8;      // chunks at sq*8 and 32+sq*8
  unsigned short* sb = Bs + srow * LDR + sq * 8;
  const unsigned short* pa0 = As + (wr + fr) * LDR + fg * 8;
  const unsigned short* pb0 = Bs + (wc + fr) * LDR + fg * 8;

  uint4 va0 = *(const uint4*)(gx + sq * 8);
  uint4 va1 = *(const uint4*)(gx + 32 + sq * 8);
  uint4 vb0 = *(const uint4*)(gk + sq * 8);
  uint4 vb1 = *(const uint4*)(gk + 32 + sq * 8);

  f32x4 acc[2][2] = {};
  for (int t = 0; t < 13; ++t) {
    __syncthreads();
    *(uint4*)sa = va0; *(uint4*)(sa + 32) = va1;
    *(uint4*)sb = vb0; *(uint4*)(sb + 32) = vb1;
    __syncthreads();
    if (t < 12) {
      int k1 = (t + 1) * 64;
      va0 = *(const uint4*)(gx + k1 + sq * 8);
      va1 = *(const uint4*)(gx + k1 + 32 + sq * 8);
      vb0 = *(const uint4*)(gk + k1 + sq * 8);
      vb1 = *(const uint4*)(gk + k1 + 32 + sq * 8);
    }
    #pragma unroll
    for (int kk = 0; kk < 64; kk += 32) {
      s16x8 a0 = *(const s16x8*)(pa0 + kk);
      s16x8 a1 = *(const s16x8*)(pa0 + 16 * LDR + kk);
      s16x8 b0 = *(const s16x8*)(pb0 + kk);
      s16x8 b1 = *(const s16x8*)(pb0 + 16 * LDR + kk);
      acc[0][0] = __builtin_amdgcn_mfma_f32_16x16x32_bf16(a0, b0, acc[0][0], 0, 0, 0);
      acc[0][1] = __builtin_amdgcn_mfma_f32_16x16x32_bf16(a0, b1, acc[0][1], 0, 0, 0);
      acc[1][0] = __builtin_amdgcn_mfma_f32_16x16x32_bf16(a1, b0, acc[1][0], 0, 0, 0);
      acc[1][1] = __builtin_amdgcn_mfma_f32_16x16x32_bf16(a1, b1, acc[1][1], 0, 0, 0);
    }
  }
  #pragma unroll
  for (int m = 0; m < 2; ++m)
    #pragma unroll
    for (int n = 0; n < 2; ++n)
      #pragma unroll
      for (int j = 0; j < 4; ++j) {
        int r = row0 + wr + m * 16 + fg * 4 + j;
        int c = col0 + wc + n * 16 + fr;
        cosb[(size_t)r * E_ + c] = acc[m][n][j];
      }
}

// ---- topk: one row per block; bitonic threshold -> LDS compact -> wave-per-candidate
//      coalesced fp32 refine -> bitonic top-8 -> direct per-expert bucket scatter ----
__global__ __launch_bounds__(256) void topk_select(const float* __restrict__ cosb,
                                                   const float* __restrict__ x,
                                                   const float* __restrict__ keys,
                                                   float* __restrict__ sims,
                                                   float* __restrict__ wsum,
                                                   int* __restrict__ count,
                                                   int* __restrict__ list) {
  __shared__ float sTop[32];
  __shared__ int   sIdx[CAP];
  __shared__ float sVal[CAP];
  __shared__ int   sCnt;
  __shared__ float sT8;
  const int tid = threadIdx.x, w = tid >> 6, lane = tid & 63;
  const int row = blockIdx.x;
  if (tid == 0) sCnt = 0;

  const float* cr = cosb + (size_t)row * E_;
  float vals[4];
  #pragma unroll
  for (int j = 0; j < 4; ++j) vals[j] = cr[j * 256 + tid];
  float lm = fmaxf(fmaxf(vals[0], vals[1]), fmaxf(vals[2], vals[3]));

  float v = lm;
  #pragma unroll
  for (int k = 2; k <= 64; k <<= 1) {
    #pragma unroll
    for (int j = k >> 1; j > 0; j >>= 1) {
      float o = __shfl_xor(v, j, 64);
      bool lower = (lane & j) == 0;
      bool asc = (lane & k) == 0;
      float mn = fminf(v, o), mx = fmaxf(v, o);
      v = (lower == asc) ? mn : mx;
    }
  }
  if (lane >= 56) sTop[w * 8 + (lane - 56)] = v;
  __syncthreads();

  if (w == 0) {
    float u = (lane < 32) ? sTop[lane] : -__builtin_inff();
    #pragma unroll
    for (int k = 2; k <= 64; k <<= 1) {
      #pragma unroll
      for (int j = k >> 1; j > 0; j >>= 1) {
        float o = __shfl_xor(u, j, 64);
        bool lower = (lane & j) == 0;
        bool asc = (lane & k) == 0;
        float mn = fminf(u, o), mx = fmaxf(u, o);
        u = (lower == asc) ? mn : mx;
      }
    }
    if (lane == 56) sT8 = u - 0.06f;   // margin >> bf16 dot error
  }
  __syncthreads();
  const float t8 = sT8;

  #pragma unroll
  for (int j = 0; j < 4; ++j) {
    if (vals[j] >= t8) {
      int pos = atomicAdd(&sCnt, 1);
      if (pos < CAP) sIdx[pos] = j * 256 + tid;
    }
  }
  __syncthreads();
  const int m = sCnt < CAP ? sCnt : CAP;

  const float4* xp4 = (const float4*)(x + (size_t)row * D_);
  float4 xr[4];
  #pragma unroll
  for (int i = 0; i < 3; ++i) xr[i] = xp4[i * 64 + lane];
  xr[3] = make_float4(0.f, 0.f, 0.f, 0.f);
  if (lane < 4) xr[3] = xp4[192 + lane];
  float q = 0.f;
  #pragma unroll
  for (int i = 0; i < 4; ++i)
    q += xr[i].x * xr[i].x + xr[i].y * xr[i].y + xr[i].z * xr[i].z + xr[i].w * xr[i].w;
  q = wave_reduce_sum(q);
  const float rn = 1.0f / fmaxf(sqrtf(q), 1e-12f);

  for (int c = w; c < m; c += 4) {
    const float4* kp4 = (const float4*)(keys + (size_t)sIdx[c] * D_);
    float s = 0.f;
    #pragma unroll
    for (int i = 0; i < 3; ++i) {
      float4 kv = kp4[i * 64 + lane];
      s += xr[i].x * kv.x + xr[i].y * kv.y + xr[i].z * kv.z + xr[i].w * kv.w;
    }
    if (lane < 4) {
      float4 kv = kp4[192 + lane];
      s += xr[3].x * kv.x + xr[3].y * kv.y + xr[3].z * kv.z + xr[3].w * kv.w;
    }
    s = wave_reduce_sum(s);
    if (lane == 0) sVal[c] = s;
  }
  __syncthreads();

  if (w == 0) {
    unsigned long long key = 0;
    if (lane < m) {
      float ev = sVal[lane];
      int ei = sIdx[lane];
      unsigned ub = __float_as_uint(ev);
      ub = (ub & 0x80000000u) ? ~ub : (ub | 0x80000000u);
      key = ((unsigned long long)ub << 32) | (unsigned)(~ei);
    }
    #pragma unroll
    for (int k = 2; k <= 64; k <<= 1) {
      #pragma unroll
      for (int j = k >> 1; j > 0; j >>= 1) {
        unsigned long long o = __shfl_xor(key, j, 64);
        bool lower = (lane & j) == 0;
        bool asc = (lane & k) == 0;
        unsigned long long mn = key < o ? key : o;
        unsigned long long mx = key < o ? o : key;
        key = (lower == asc) ? mn : mx;
      }
    }
    if (lane >= 56) {
      unsigned ub = (unsigned)(key >> 32);
      unsigned fb = (ub & 0x80000000u) ? (ub ^ 0x80000000u) : ~ub;
      float ev = __uint_as_float(fb);
      int ei = (int)(~(unsigned)key) & (E_ - 1);
      float simv = ev * rn;
      int r = 63 - lane;                      // rank, 0 = best
      sims[row * K_ + r] = simv;
      float ssum = simv;
      ssum += __shfl_xor(ssum, 1, 64);
      ssum += __shfl_xor(ssum, 2, 64);
      ssum += __shfl_xor(ssum, 4, 64);
      if (lane == 56) wsum[row] = ssum;
      // ascending sort of the 8 expert ids; lane 56+j holds j-th smallest
      int si = ei;
      const int l3 = lane & 7;
      #pragma unroll
      for (int k = 2; k <= 8; k <<= 1) {
        #pragma unroll
        for (int j = k >> 1; j > 0; j >>= 1) {
          int o = __shfl_xor(si, j, 64);
          bool lower = (l3 & j) == 0;
          bool asc = (l3 & k) == 0;
          int mn = si < o ? si : o;
          int mx = si < o ? o : si;
          si = (lower == asc) ? mn : mx;
        }
      }
      int pos = atomicAdd(&count[si], 1);
      if (pos < ECAP) list[si * ECAP + pos] = row * K_ + (lane - 56);
    }
  }
}

// ---------------- per-expert bf16 MFMA: X_e @ W_e^T -> tanh -> slot ----------------
__global__ __launch_bounds__(256) void expert_mfma(const float* __restrict__ Wm,
                                                   const float* __restrict__ bm,
                                                   const unsigned short* __restrict__ xh,
                                                   const int* __restrict__ list,
                                                   const int* __restrict__ count,
                                                   float* __restrict__ slot) {
  __shared__ unsigned short Wl[16 * LDW];
  const int e   = blockIdx.x;
  const int tid = threadIdx.x;
  int n = count[e];
  n = n < ECAP ? n : ECAP;
  const int base = e * ECAP;

  for (int ch = tid; ch < 16 * CHR; ch += 256) {
    int r  = ch / CHR;
    int kc = (ch % CHR) * 8;
    unsigned short u[8];
    if (r < 10 && kc < 784) {
      const float* src = Wm + (size_t)e * (C_ * D_) + r * D_ + kc;
      #pragma unroll
      for (int i = 0; i < 8; ++i) {
        __hip_bfloat16 h = __float2bfloat16(src[i]);
        u[i] = *(unsigned short*)&h;
      }
    } else {
      #pragma unroll
      for (int i = 0; i < 8; ++i) u[i] = 0;
    }
    *(uint4*)(Wl + r * LDW + kc) = *(uint4*)u;
  }
  __syncthreads();
  if (n == 0) return;

  const int lane = tid & 63, w = tid >> 6;
  const int fr = lane & 15, fg = lane >> 4;
  const float bias = (fr < C_) ? bm[e * C_ + fr] : 0.f;
  const unsigned short* bp = Wl + fr * LDW + fg * 8;

  for (int c0 = w * 16; c0 < n; c0 += 64) {
    int sidx = c0 + fr;
    int item = (sidx < n) ? list[base + sidx] : list[base];
    const unsigned short* xrow = xh + (size_t)(item >> 3) * KP + fg * 8;
    f32x4 acc = {};
    #pragma unroll
    for (int k0 = 0; k0 < KP; k0 += 32) {
      s16x8 a = *(const s16x8*)(xrow + k0);
      s16x8 b = *(const s16x8*)(bp + k0);
      acc = __builtin_amdgcn_mfma_f32_16x16x32_bf16(a, b, acc, 0, 0, 0);
    }
    if (fr < C_) {
      #pragma unroll
      for (int j = 0; j < 4; ++j) {
        int s2 = c0 + fg * 4 + j;
        if (s2 < n) {
          int it2 = list[base + s2];
          slot[(size_t)it2 * C_ + fr] = tanhf((acc[j] + bias) * 0.1f) * 10.0f;
        }
      }
    }
  }
}

// ---- heads via MFMA (+fused ensemble weighted-reduce for the same 64 rows) ----
__global__ __launch_bounds__(256) void heads_mfma(const unsigned short* __restrict__ xh,
                                                  const unsigned short* __restrict__ Wh,
                                                  const float* __restrict__ bv,
                                                  const float* __restrict__ bt,
                                                  const float* __restrict__ slot,
                                                  const float* __restrict__ sims,
                                                  const float* __restrict__ wsum,
                                                  float* __restrict__ out_ens,
                                                  float* __restrict__ out_tanh,
                                                  float* __restrict__ out_van) {
  const int tid = threadIdx.x, w = tid >> 6, lane = tid & 63;
  const int fr = lane & 15, fg = lane >> 4;
  const int rbase0 = blockIdx.x * 64;
  const int rbase = rbase0 + w * 16;
  const unsigned short* ar  = xh + (size_t)(rbase + fr) * KP + fg * 8;
  const unsigned short* b0p = Wh + (size_t)fr * KP + fg * 8;
  const unsigned short* b1p = Wh + (size_t)(fr + 16) * KP + fg * 8;
  f32x4 acc0 = {}, acc1 = {};
  #pragma unroll 2
  for (int k0 = 0; k0 < KP; k0 += 32) {
    s16x8 a  = *(const s16x8*)(ar + k0);
    s16x8 b0 = *(const s16x8*)(b0p + k0);
    s16x8 b1 = *(const s16x8*)(b1p + k0);
    acc0 = __builtin_amdgcn_mfma_f32_16x16x32_bf16(a, b0, acc0, 0, 0, 0);
    acc1 = __builtin_amdgcn_mfma_f32_16x16x32_bf16(a, b1, acc1, 0, 0, 0);
  }
  const float bvv = (fr < C_) ? bv[fr] : 0.f;
  const float btv = (fr < C_) ? bt[fr] : 0.f;
  #pragma unroll
  for (int j = 0; j < 4; ++j) {
    int r = rbase + fg * 4 + j;
    float vv = acc0[j] + bvv;
    float tv = acc1[j] + btv;
    float mv = (fr < C_) ? vv : -__builtin_inff();
    #pragma unroll
    for (int off = 1; off < 16; off <<= 1) mv = fmaxf(mv, __shfl_xor(mv, off, 64));
    float ev = (fr < C_) ? expf(vv - mv) : 0.f;
    float se = ev;
    #pragma unroll
    for (int off = 1; off < 16; off <<= 1) se += __shfl_xor(se, off, 64);
    float lse = mv + logf(se);
    if (fr < C_) {
      out_van[(size_t)r * C_ + fr]  = vv - lse;
      out_tanh[(size_t)r * C_ + fr] = tanhf(tv * 0.1f) * 10.0f;
    }
  }
  // fused ensemble reduce for rows [rbase0, rbase0+64)
  for (int idx = tid; idx < 64 * C_; idx += 256) {
    int b = rbase0 + idx / C_, c = idx % C_;
    float acc = 0.f;
    #pragma unroll
    for (int k = 0; k < K_; ++k)
      acc += slot[(size_t)(b * K_ + k) * C_ + c] * sims[b * K_ + k];
    out_ens[(size_t)b * C_ + c] = acc / wsum[b];
  }
}

extern "C" void kernel_launch(void* const* d_in, const int* in_sizes, int n_in,
                              void* d_out, int out_size, void* d_ws, size_t ws_size,
                              hipStream_t stream) {
  const float* x    = (const float*)d_in[0];
  const float* keys = (const float*)d_in[1];
  const float* Wm   = (const float*)d_in[2];
  const float* bm   = (const float*)d_in[3];
  const float* Wv   = (const float*)d_in[4];
  const float* bv   = (const float*)d_in[5];
  const float* Wt   = (const float*)d_in[6];
  const float* bt   = (const float*)d_in[7];
  float* out = (float*)d_out;

  char* p = (char*)d_ws;
  auto carve = [&](size_t bytes) { char* q = p; p += (bytes + 255) & ~(size_t)255; return q; };
  float* cosb  = (float*)carve((size_t)B_ * E_ * 4);
  float* sims  = (float*)carve(B_ * K_ * 4);
  float* wsumb = (float*)carve(B_ * 4);
  unsigned short* xh = (unsigned short*)carve((size_t)B_ * KP * 2);
  unsigned short* kh = (unsigned short*)carve((size_t)E_ * KP * 2);
  unsigned short* Wh = (unsigned short*)carve((size_t)32 * KP * 2);
  int*   count  = (int*)carve(E_ * 4);
  int*   list   = (int*)carve((size_t)E_ * ECAP * 4);
  float* slot   = (float*)carve((size_t)B_ * K_ * C_ * 4);

  int prep_blocks = ((B_ + E_ + 32) * CHR) / 256;   // 535808/256 = 2093
  prep_all<<<prep_blocks, 256, 0, stream>>>(x, keys, Wv, Wt, xh, kh, Wh, count);
  dim3 g(E_ / 64, B_ / 64);
  gemm_bf16<<<g, 256, 0, stream>>>(xh, kh, cosb);
  topk_select<<<B_, 256, 0, stream>>>(cosb, x, keys, sims, wsumb, count, list);
  expert_mfma<<<E_, 256, 0, stream>>>(Wm, bm, xh, list, count, slot);
  heads_mfma<<<B_ / 64, 256, 0, stream>>>(xh, Wh, bv, bt, slot, sims, wsumb,
                                          out,
                                          out + (size_t)B_ * C_,
                                          out + 2 * (size_t)B_ * C_);
}